// Round 3
// baseline (666.431 us; speedup 1.0000x reference)
//
#include <hip/hip_runtime.h>
#include <math.h>

// SparseEdgeEmbeddingV3: out[1, N, N, 16] fp32, N=3072.
// keep(i,j) = exp(-d2/18) >= 0.9 && d2 > 0 && i != j   (sig_max = 3.0)
// out[i,j,c] = keep ? exp(-d2 / (2*sigma_c^2)) : 0
//
// R7: TWO-PASS. Evidence: R4 (one-shot), R5 (shuffle), R6 (persistent+LDS)
// all plateau at ~3 TB/s of stores while rocclr fillBufferAligned sustains
// 6.26 TB/s in the same window. Dispatch overhead, VALU count, and occupancy
// are each ruled out by one of R4/R5/R6. Common factor left: every version
// interleaves compute with the store stream. R7 separates them:
//   Pass 1: pure grid-stride zero-fill (store-only, fill-clone structure)
//           -> should run at fill BW: 604 MB @ ~6.3 TB/s ~= 96 us.
//   Pass 2: sparse patch — compute d2/keep per pair, write ONLY the ~1.3%
//           kept 64-B lines (16 exp values). ~8 MB of scattered full-line
//           writes + compute-only for the rest. Stream-serialized after
//           pass 1, so kept lines are written exactly once after the zeros.
// This is also the decisive experiment: if pass 1 does NOT reach fill BW,
// the cap is store-mode (nt/sc0), not kernel structure.
//
// KEEP decision numerics bit-identical to R1..R6 (matches numpy boundary
// behavior on this fixed input — do not touch):
//   sq = (x*x + y*y) + z*z  (rn, no fma)
//   dot = fma(z,z, fma(y,y, x*x))
//   d2 = max((sqi+sqj) - 2*dot, 0)
//   d2<=1.8 keep, d2>2.0 drop, band decided by f64 exp(fp32(-d2/18)) >= 0.9
// Kept VALUES only need |err| << 0.02 -> native rcp + __expf (unchanged).

constexpr int N_PTS = 3072;
constexpr int N4_OUT = N_PTS * N_PTS * 4;   // float4 slots in out (37.7M)

// ---------------- Pass 1: pure zero-fill, fill-clone structure -------------
__global__ __launch_bounds__(256) void zero_fill_kernel(float4* __restrict__ out)
{
    const float4 z = make_float4(0.0f, 0.0f, 0.0f, 0.0f);
    const int stride = gridDim.x << 8;
    int idx = (blockIdx.x << 8) + threadIdx.x;
#pragma unroll 4
    for (; idx < N4_OUT; idx += stride) {
        out[idx] = z;          // wave: 1 KB contiguous; no loads, no branches
    }
}

// ---------------- Pass 2: sparse patch of kept pairs -----------------------
__global__ __launch_bounds__(1024) void sparse_patch_kernel(
    const float* __restrict__ coord,   // [N,3]
    const float* __restrict__ sigma,   // [16]
    float* __restrict__ out)           // [N,N,16]
{
    const int i = blockIdx.y;
    const int j = (blockIdx.x << 10) + threadIdx.x;

    // i-coords are wave-uniform -> scalar loads; same IEEE ops as always.
    const float xi = coord[3 * i + 0], yi = coord[3 * i + 1], zi = coord[3 * i + 2];
    const float xj = coord[3 * j + 0], yj = coord[3 * j + 1], zj = coord[3 * j + 2];

    // --- keep decision: EXACT R1..R6 numerics ---
    float sqi = __fadd_rn(__fadd_rn(__fmul_rn(xi, xi), __fmul_rn(yi, yi)),
                          __fmul_rn(zi, zi));
    float sqj = __fadd_rn(__fadd_rn(__fmul_rn(xj, xj), __fmul_rn(yj, yj)),
                          __fmul_rn(zj, zj));
    float dot = __fmul_rn(xi, xj);
    dot = __builtin_fmaf(yi, yj, dot);
    dot = __builtin_fmaf(zi, zj, dot);

    float d2 = __fsub_rn(__fadd_rn(sqi, sqj), __fmul_rn(2.0f, dot));
    d2 = fmaxf(d2, 0.0f);

    bool keep = (i != j) && (d2 > 0.0f) && !(d2 > 2.0f);
    if (keep && d2 > 1.8f) {
        // Rare band (~0.4% of pairs): numpy-matching arithmetic.
        float smax = sigma[15];                                  // 3.0
        float den  = __fmul_rn(__fmul_rn(2.0f, smax), smax);     // 18.0 exact
        float qf   = __fdiv_rn(-d2, den);                        // fp32 rn
        keep = (exp((double)qf) >= 0.9);
    }

    if (keep) {
        // ~1.3% of pairs: write the full 64-B line (all 16 channels kept).
        const float4* s4 = reinterpret_cast<const float4*>(sigma);
        float4* line = reinterpret_cast<float4*>(out)
                     + (((size_t)i * N_PTS + j) << 2);
#pragma unroll
        for (int q = 0; q < 4; ++q) {
            const float4 s = s4[q];
            float4 v;
            v.x = __expf(-d2 * __builtin_amdgcn_rcpf(2.0f * s.x * s.x));
            v.y = __expf(-d2 * __builtin_amdgcn_rcpf(2.0f * s.y * s.y));
            v.z = __expf(-d2 * __builtin_amdgcn_rcpf(2.0f * s.z * s.z));
            v.w = __expf(-d2 * __builtin_amdgcn_rcpf(2.0f * s.w * s.w));
            line[q] = v;
        }
    }
}

extern "C" void kernel_launch(void* const* d_in, const int* in_sizes, int n_in,
                              void* d_out, int out_size, void* d_ws, size_t ws_size,
                              hipStream_t stream) {
    const float* coord = (const float*)d_in[0];   // [3072, 3] fp32
    const float* sigma = (const float*)d_in[1];   // [16] fp32
    float* out = (float*)d_out;                   // [1, 3072, 3072, 16] fp32

    // Pass 1: zero the whole output at (hopefully) fill bandwidth.
    hipLaunchKernelGGL(zero_fill_kernel, dim3(2048), dim3(256), 0, stream,
                       reinterpret_cast<float4*>(out));

    // Pass 2: patch kept entries (stream-ordered after pass 1).
    hipLaunchKernelGGL(sparse_patch_kernel, dim3(N_PTS / 1024, N_PTS),
                       dim3(1024), 0, stream, coord, sigma, out);
}

// Round 4
// 588.441 us; speedup vs baseline: 1.1325x; 1.1325x over previous
//
#include <hip/hip_runtime.h>
#include <math.h>

// SparseEdgeEmbeddingV3: out[1, N, N, 16] fp32, N=3072.
// keep(i,j) = exp(-d2/18) >= 0.9 && d2 > 0 && i != j   (sig_max = 3.0)
// out[i,j,c] = keep ? exp(-d2 / (2*sigma_c^2)) : 0
//
// R8 = R4 (best, 563.8 us) + 4 independent stores per thread.
// Post-mortem ledger:
//   R5 (cut VALU 4x)            -> regressed  => not VALU-bound
//   R6 (persistent + streaming) -> regressed  => not dispatch/turnover-bound
//   R7 (pure-store grid-stride) -> ~2.5 TB/s  => not compute-interleave-bound
//   rocclr fill: FETCH_SIZE=14.5 KB at 6.27 TB/s plain stores => no RFO on
//     full-line plain stores; flags are not the difference.
// Surviving theory: per-wave store concurrency. The fill's long-lived waves
// keep many independent stores in vmcnt flight; R4's waves issue exactly ONE
// store then drain at s_endpgm; R6's stores were serialized by LDS latency.
// R8 keeps R4's one-shot 2D structure and 1 KB/wave-instr contiguity but
// gives every thread 4 independent pair-pipelines -> 4 back-to-back stores
// outstanding per wave, and sigma/rcps/coord_i amortized 4x.
//
// KEEP decision numerics bit-identical to R1..R7 (matches numpy boundary
// behavior on this fixed input — do not touch):
//   sq = (x*x + y*y) + z*z  (rn, no fma)
//   dot = fma(z,z, fma(y,y, x*x))
//   d2 = max((sqi+sqj) - 2*dot, 0)
//   d2<=1.8 keep, d2>2.0 drop, band decided by f64 exp(fp32(-d2/18)) >= 0.9
// Kept VALUES only need |err| << 0.02 -> native rcp + __expf (unchanged).

constexpr int N_PTS = 3072;

__global__ __launch_bounds__(256) void sparse_edge_kernel(
    const float* __restrict__ coord,   // [N,3]
    const float* __restrict__ sigma,   // [16]
    float* __restrict__ out)           // [N,N,16]
{
    const int tid = threadIdx.x;
    const int i   = blockIdx.y;
    const int jb  = (blockIdx.x << 8) + (tid >> 2);  // block covers 256 pairs
    const int c4  = tid & 3;

    // Hoisted setup (R4 paid all of this per single pair).
    const float xi = coord[3 * i + 0], yi = coord[3 * i + 1], zi = coord[3 * i + 2];
    const float sqi = __fadd_rn(__fadd_rn(__fmul_rn(xi, xi), __fmul_rn(yi, yi)),
                                __fmul_rn(zi, zi));
    const float4 s = reinterpret_cast<const float4*>(sigma)[c4];
    // inv = 1/(2*s*s) via native rcp; value tolerance is 0.02, err ~1e-7.
    const float i0 = __builtin_amdgcn_rcpf(2.0f * s.x * s.x);
    const float i1 = __builtin_amdgcn_rcpf(2.0f * s.y * s.y);
    const float i2 = __builtin_amdgcn_rcpf(2.0f * s.z * s.z);
    const float i3 = __builtin_amdgcn_rcpf(2.0f * s.w * s.w);
    const float smax = sigma[15];                               // 3.0
    const float den  = __fmul_rn(__fmul_rn(2.0f, smax), smax);  // 18.0 exact

    // float4 slot (i*N + jb + 64*sub)*4 + c4 == base + sub*256 + tid.
    float4* __restrict__ p = reinterpret_cast<float4*>(out)
                           + ((size_t)i * N_PTS << 2) + ((size_t)blockIdx.x << 10);

#pragma unroll
    for (int sub = 0; sub < 4; ++sub) {
        const int j = jb + (sub << 6);

        const float xj = coord[3 * j + 0];
        const float yj = coord[3 * j + 1];
        const float zj = coord[3 * j + 2];

        // --- keep decision: EXACT R1..R7 numerics ---
        const float sqj = __fadd_rn(__fadd_rn(__fmul_rn(xj, xj), __fmul_rn(yj, yj)),
                                    __fmul_rn(zj, zj));
        float dot = __fmul_rn(xi, xj);
        dot = __builtin_fmaf(yi, yj, dot);
        dot = __builtin_fmaf(zi, zj, dot);

        float d2 = __fsub_rn(__fadd_rn(sqi, sqj), __fmul_rn(2.0f, dot));
        d2 = fmaxf(d2, 0.0f);

        bool keep = (i != j) && (d2 > 0.0f) && !(d2 > 2.0f);
        if (keep && d2 > 1.8f) {
            // Rare band (~0.4% of pairs): numpy-matching arithmetic.
            float qf = __fdiv_rn(-d2, den);   // fp32 rn
            keep = (exp((double)qf) >= 0.9);
        }

        float4 v = make_float4(0.0f, 0.0f, 0.0f, 0.0f);
        if (keep) {
            v.x = __expf(-d2 * i0);
            v.y = __expf(-d2 * i1);
            v.z = __expf(-d2 * i2);
            v.w = __expf(-d2 * i3);
        }

        // Plain store (R4 finding: plain > nontemporal). 4 independent
        // stores per thread queue back-to-back; drained once at endpgm.
        p[(sub << 8) + tid] = v;
    }
}

extern "C" void kernel_launch(void* const* d_in, const int* in_sizes, int n_in,
                              void* d_out, int out_size, void* d_ws, size_t ws_size,
                              hipStream_t stream) {
    const float* coord = (const float*)d_in[0];   // [3072, 3] fp32
    const float* sigma = (const float*)d_in[1];   // [16] fp32
    float* out = (float*)d_out;                   // [1, 3072, 3072, 16] fp32

    dim3 grid(N_PTS / 256, N_PTS);   // (12, 3072): 16 KB contiguous per block
    dim3 block(256);
    hipLaunchKernelGGL(sparse_edge_kernel, grid, block, 0, stream,
                       coord, sigma, out);
}